// Round 11
// baseline (20076.376 us; speedup 1.0000x reference)
//
#include <hip/hip_runtime.h>

typedef __bf16 bf16;
typedef __bf16 bf16x8 __attribute__((ext_vector_type(8)));
typedef __bf16 bf16x4 __attribute__((ext_vector_type(4)));
typedef float  f32x4  __attribute__((ext_vector_type(4)));
typedef unsigned int u32;

#define B_TOT 4096
#define T_SEQ 64
#define NT_OUT 8
#define NTHR 512
#define NBLK 512
#define GSZ  16

// ---- ws layout (bytes) ----
#define WS_W0   0           // 512x256 bf16 packed frags
#define WS_W1   262144
#define WS_W2   786432
#define WS_WHH  1048576
#define WS_WIH  1441792
#define WS_BC   1490944     // 64x768 f32
#define WS_GY   1703936     // 32 groups x 64KB   (y_stage / GRU h buf0)
#define WS_GYB  3801088     // 32 x 64KB          (GRU h buf1)
#define WS_GH1  5898240     // 32 x 128KB
#define WS_GH2  10092544    // 32 x 128KB
#define WS_FLG  14286848    // 32 groups x 256B: fY@+0, fH1@+64B, fH2@+128B (NO aliasing)
#define WS_MAP  14295040    // 512 u32 xcd map; gctr @ +2048

// Tsit5 tableau
constexpr float A21 = 0.161f;
constexpr float A31 = -0.008480655492356989f, A32 = 0.335480655492357f;
constexpr float A41 = 2.8971530571054935f, A42 = -6.359448489975075f, A43 = 4.362295432869581f;
constexpr float A51 = 5.325864828439257f, A52 = -11.748883564062828f, A53 = 7.4955393428898365f, A54 = -0.09249506636175525f;
constexpr float A61 = 5.86145544294642f, A62 = -12.92096931784711f, A63 = 8.159367898576159f, A64 = -0.071584973281401f, A65 = -0.028269050394068383f;
constexpr float BC1 = 0.09646076681806523f, BC2 = 0.01f, BC3 = 0.4798896504144996f;
constexpr float BC4 = 1.379008574103742f, BC5 = -3.290069515436081f, BC6 = 2.324710524099774f;
constexpr float DT = 0.1f;
constexpr float BROW[5][5] = {
    {A21, 0, 0, 0, 0},
    {A31, A32, 0, 0, 0},
    {A41, A42, A43, 0, 0},
    {A51, A52, A53, A54, 0},
    {A61, A62, A63, A64, A65}};
constexpr float FCF[6] = {BC1, BC2, BC3, BC4, BC5, BC6};

__device__ __forceinline__ f32x4 MFMA(bf16x8 a, bf16x8 b, f32x4 c) {
    return __builtin_amdgcn_mfma_f32_16x16x32_bf16(a, b, c, 0, 0, 0);
}
__device__ __forceinline__ float eluf(float x) { return x > 0.f ? x : __expf(x) - 1.f; }
__device__ __forceinline__ float sigm_f(float x) { return 1.f / (1.f + __expf(-x)); }
__device__ __forceinline__ float tanh_f(float x) { return 1.f - 2.f / (__expf(2.f * x) + 1.f); }

// ---- coherent global access (FAST: group formed on one XCD -> sc0 only) ----
template<bool FAST>
__device__ __forceinline__ void ld4g(const bf16* p, bf16x8& a0, bf16x8& a1, bf16x8& a2, bf16x8& a3) {
    if constexpr (FAST) {
        asm volatile(
            "global_load_dwordx4 %0, %4, off sc0\n\t"
            "global_load_dwordx4 %1, %4, off offset:1024 sc0\n\t"
            "global_load_dwordx4 %2, %4, off offset:2048 sc0\n\t"
            "global_load_dwordx4 %3, %4, off offset:3072 sc0"
            : "=&v"(a0), "=&v"(a1), "=&v"(a2), "=&v"(a3) : "v"(p) : "memory");
    } else {
        asm volatile(
            "global_load_dwordx4 %0, %4, off sc0 sc1\n\t"
            "global_load_dwordx4 %1, %4, off offset:1024 sc0 sc1\n\t"
            "global_load_dwordx4 %2, %4, off offset:2048 sc0 sc1\n\t"
            "global_load_dwordx4 %3, %4, off offset:3072 sc0 sc1"
            : "=&v"(a0), "=&v"(a1), "=&v"(a2), "=&v"(a3) : "v"(p) : "memory");
    }
}
template<bool FAST>
__device__ __forceinline__ bf16x8 ld1g(const bf16* p) {
    bf16x8 a;
    if constexpr (FAST)
        asm volatile("global_load_dwordx4 %0, %1, off sc0\n\ts_waitcnt vmcnt(0)"
                     : "=v"(a) : "v"(p) : "memory");
    else
        asm volatile("global_load_dwordx4 %0, %1, off sc0 sc1\n\ts_waitcnt vmcnt(0)"
                     : "=v"(a) : "v"(p) : "memory");
    return a;
}
template<bool FAST>
__device__ __forceinline__ void st4g(bf16* p, bf16x4 v) {
    if constexpr (FAST) *(bf16x4*)p = v;
    else asm volatile("global_store_dwordx2 %0, %1, off sc0 sc1" :: "v"(p), "v"(v) : "memory");
}
__device__ __forceinline__ void vmwait() {
    asm volatile("s_waitcnt vmcnt(0)" ::: "memory");
    __builtin_amdgcn_sched_barrier(0);
}

// ---- block-lockstep rendezvous (round-5 proven semantics; sound flag layout) ----
__device__ __forceinline__ void produce(u32* f, int tid) {
    asm volatile("s_waitcnt vmcnt(0)" ::: "memory");   // own wave's stores acked
    __syncthreads();                                   // all waves drained
    if (tid == 0) __hip_atomic_fetch_add(f, 1u, __ATOMIC_RELAXED, __HIP_MEMORY_SCOPE_AGENT);
}
// all waves spin directly; each exits when the group count is reached (no barrier)
__device__ __forceinline__ void consume(const u32* f, u32 tgt) {
    while (__hip_atomic_load(f, __ATOMIC_RELAXED, __HIP_MEMORY_SCOPE_AGENT) < tgt)
        __builtin_amdgcn_s_sleep(1);
}

// ---- one Tsit5 stage; wave = batch tile w; block j owns 16-feat output slices ----
template<int ST, bool FAST>
__device__ __forceinline__ void ode_stage(
    const bf16* sW0, const bf16* sW1, const bf16* sW2,
    bf16* gY, bf16* gH1, bf16* gH2,
    u32* fY, u32* fH1, u32* fH2, int tid, int w, int lane,
    const f32x4 (&b0v)[2], const f32x4 (&b1v)[2], const f32x4& b2v,
    const int (&dA)[2], int dY,
    f32x4& yreg, f32x4 (&kreg)[5],
    u32& eY, u32& eH1, u32& eH2) {
    const f32x4 Z = {0.f, 0.f, 0.f, 0.f};
    // ---- L0: h1 feats [32j..32j+32) = elu(W0s x y^T + b0s) ----
    {
        bf16x8 a[8];
        const bf16* p = gY + w * 4096 + lane * 8;
        ld4g<FAST>(p, a[0], a[1], a[2], a[3]);
        ld4g<FAST>(p + 2048, a[4], a[5], a[6], a[7]);
        vmwait();
        f32x4 acc[2] = {Z, Z};
        #pragma unroll
        for (int kk = 0; kk < 8; ++kk)
            #pragma unroll
            for (int nt = 0; nt < 2; ++nt)
                acc[nt] = MFMA(*(const bf16x8*)&sW0[(nt * 8 + kk) * 512 + lane * 8], a[kk], acc[nt]);
        #pragma unroll
        for (int nt = 0; nt < 2; ++nt) {
            bf16x4 ov;
            #pragma unroll
            for (int r = 0; r < 4; ++r) ov[r] = (bf16)eluf(acc[nt][r] + b0v[nt][r]);
            st4g<FAST>(gH1 + w * 8192 + dA[nt], ov);
        }
    }
    produce(fH1, tid); ++eH1;
    consume(fH1, GSZ * eH1);
    // ---- L1: h2 feats [32j..32j+32) = elu(W1s x h1^T + b1s) ----
    {
        bf16x8 a[16];
        const bf16* p = gH1 + w * 8192 + lane * 8;
        ld4g<FAST>(p, a[0], a[1], a[2], a[3]);
        ld4g<FAST>(p + 2048, a[4], a[5], a[6], a[7]);
        ld4g<FAST>(p + 4096, a[8], a[9], a[10], a[11]);
        ld4g<FAST>(p + 6144, a[12], a[13], a[14], a[15]);
        vmwait();
        f32x4 acc[2] = {Z, Z};
        #pragma unroll
        for (int kk = 0; kk < 16; ++kk)
            #pragma unroll
            for (int nt = 0; nt < 2; ++nt)
                acc[nt] = MFMA(*(const bf16x8*)&sW1[(nt * 16 + kk) * 512 + lane * 8], a[kk], acc[nt]);
        #pragma unroll
        for (int nt = 0; nt < 2; ++nt) {
            bf16x4 ov;
            #pragma unroll
            for (int r = 0; r < 4; ++r) ov[r] = (bf16)eluf(acc[nt][r] + b1v[nt][r]);
            st4g<FAST>(gH2 + w * 8192 + dA[nt], ov);
        }
    }
    produce(fH2, tid); ++eH2;
    consume(fH2, GSZ * eH2);
    // ---- L2: k feats [16j..16j+16) = W2s x h2^T + b2s; Tsit5 build ----
    {
        bf16x8 a[16];
        const bf16* p = gH2 + w * 8192 + lane * 8;
        ld4g<FAST>(p, a[0], a[1], a[2], a[3]);
        ld4g<FAST>(p + 2048, a[4], a[5], a[6], a[7]);
        ld4g<FAST>(p + 4096, a[8], a[9], a[10], a[11]);
        ld4g<FAST>(p + 6144, a[12], a[13], a[14], a[15]);
        vmwait();
        f32x4 acc = {0.f, 0.f, 0.f, 0.f};
        #pragma unroll
        for (int kk = 0; kk < 16; ++kk)
            acc = MFMA(*(const bf16x8*)&sW2[kk * 512 + lane * 8], a[kk], acc);
        f32x4 kv;
        #pragma unroll
        for (int r = 0; r < 4; ++r) kv[r] = acc[r] + b2v[r];
        f32x4 yst;
        if constexpr (ST < 5) {
            kreg[ST] = kv;
            yst = yreg;
            #pragma unroll
            for (int s = 0; s <= ST; ++s) {
                const float c = DT * BROW[ST][s];
                #pragma unroll
                for (int r = 0; r < 4; ++r) yst[r] += c * kreg[s][r];
            }
        } else {
            #pragma unroll
            for (int s = 0; s < 5; ++s) {
                const float c = DT * FCF[s];
                #pragma unroll
                for (int r = 0; r < 4; ++r) yreg[r] += c * kreg[s][r];
            }
            #pragma unroll
            for (int r = 0; r < 4; ++r) yreg[r] += (DT * FCF[5]) * kv[r];
            yst = yreg;
        }
        bf16x4 ov;
        #pragma unroll
        for (int r = 0; r < 4; ++r) ov[r] = (bf16)yst[r];
        st4g<FAST>(gY + w * 4096 + dY, ov);
    }
    produce(fY, tid); ++eY;
}

// ---- decode: block rank j emits its group's rows [(j>>1)*16 + (j&1)*8 .. +8) ----
template<bool FAST>
__device__ __forceinline__ void dec_unit(const bf16* gY, const float* sWdec, const float* sBdec,
                                         float* out, int g, int j, int w, int lane, int H, int u) {
    const int rt = (j & 1) * 8 + w;      // row within tile (j>>1)
    const int li = lane & 31;
    const bf16* p = gY + (size_t)(j >> 1) * 4096 + ((li >> 2) * 64 + (li & 3) * 16 + rt) * 8;
    bf16x8 yv = ld1g<FAST>(p);
    const int f0 = li * 8;
    float acc[8];
    #pragma unroll
    for (int t = 0; t < 8; ++t) acc[t] = 0.f;
    #pragma unroll
    for (int e = 0; e < 8; ++e) {
        const float yf = (float)yv[e];
        #pragma unroll
        for (int t = 0; t < 8; ++t) acc[t] += yf * sWdec[t * 256 + f0 + e];
    }
    #pragma unroll
    for (int k = 1; k < 32; k <<= 1)
        #pragma unroll
        for (int t = 0; t < 8; ++t) acc[t] += __shfl_xor(acc[t], k, 64);
    if (lane == 0) {
        const size_t row = (size_t)g * 128 + (j >> 1) * 16 + rt;
        #pragma unroll
        for (int t = 0; t < 8; ++t) out[(row * H + u) * NT_OUT + t] = acc[t] + sBdec[t];
    }
}

template<bool FAST>
__device__ void body(const float* __restrict__ x_seq, const int* __restrict__ cidx,
                     const float* __restrict__ b_n, const float* __restrict__ b0,
                     const float* __restrict__ b1, const float* __restrict__ b2,
                     const float* __restrict__ W_dec, const float* __restrict__ b_dec,
                     char* __restrict__ ws, float* __restrict__ out,
                     bf16* sWgt, float* sWdec, float* sBdec,
                     int H, int g, int j) {
    const int tid = threadIdx.x, w = tid >> 6, lane = tid & 63;
    const int lm = lane & 15, q = lane >> 4, q4 = q << 2;
    const int grow0 = g * 128;

    const bf16* W0p  = (const bf16*)(ws + WS_W0);
    const bf16* W1p  = (const bf16*)(ws + WS_W1);
    const bf16* W2p  = (const bf16*)(ws + WS_W2);
    const bf16* WhhP = (const bf16*)(ws + WS_WHH);
    const bf16* WihP = (const bf16*)(ws + WS_WIH);
    const float* bias_c = (const float*)(ws + WS_BC);
    bf16* gY  = (bf16*)(ws + WS_GY)  + (size_t)g * 32768;
    bf16* gYb = (bf16*)(ws + WS_GYB) + (size_t)g * 32768;
    bf16* gH1 = (bf16*)(ws + WS_GH1) + (size_t)g * 65536;
    bf16* gH2 = (bf16*)(ws + WS_GH2) + (size_t)g * 65536;
    // 256B per group: fY@+0, fH1@+64B, fH2@+128B — all strictly inside the stride
    u32* fl  = (u32*)(ws + WS_FLG + (size_t)g * 256);
    u32 *fY = fl, *fH1 = fl + 16, *fH2 = fl + 32;

    u32 eY = 0, eH1 = 0, eH2 = 0;

    // ---- stage decode weights + GRU weight slices into LDS ----
    for (int i = tid; i < 2048; i += NTHR) sWdec[i] = W_dec[i];
    if (tid < 8) sBdec[tid] = b_dec[tid];
    // GRU slices: 3 gate c-tiles (c = gam*16 + j), 9 frags each (8 Whh + 1 Wih)
    for (int i = tid; i < 27 * 64; i += NTHR) {
        const int fr = i >> 6, l = i & 63;
        const int gam = fr / 9, kk = fr % 9;
        const int c = gam * 16 + j;
        const bf16* src = (kk < 8) ? &WhhP[(((size_t)c) * 8 + kk) * 512 + l * 8]
                                   : &WihP[((size_t)c) * 512 + l * 8];
        *(bf16x8*)&sWgt[((size_t)fr) * 512 + l * 8] = *(const bf16x8*)src;
    }

    // ---- GRU per-wave constants (wave = batch tile m = w; feats [16j..16j+16)) ----
    const int m = w;
    float bcr[4], bcz[4], bcn[4], bnr[4];
    {
        const int c = cidx[grow0 + 16 * m + lm];
        #pragma unroll
        for (int r = 0; r < 4; ++r) {
            const int F = 16 * j + q4 + r;
            bcr[r] = bias_c[(size_t)c * 768 + F];
            bcz[r] = bias_c[(size_t)c * 768 + 256 + F];
            bcn[r] = bias_c[(size_t)c * 768 + 512 + F];
            bnr[r] = b_n[F];
        }
    }
    const int dY = ((j >> 1) * 64 + (lm | (((2 * j + (q >> 1)) & 3) << 4))) * 8 + (q & 1) * 4;

    // h0 = 0 (wave w zeroes feats [16j..16j+16) of its tile)
    {
        bf16x4 z4;
        #pragma unroll
        for (int r = 0; r < 4; ++r) z4[r] = (bf16)0.f;
        st4g<FAST>(gY + m * 4096 + dY, z4);
    }
    produce(fY, tid); ++eY;     // barrier inside also covers LDS weight staging

    // ---- GRU scan (block-lockstep) ----
    f32x4 hreg = {0.f, 0.f, 0.f, 0.f};
    const f32x4 Z = {0.f, 0.f, 0.f, 0.f};
    for (int t = 0; t < T_SEQ; ++t) {
        bf16x8 ax;
        {
            const float* xp = x_seq + (((size_t)(grow0 + 16 * m + lm)) * T_SEQ + t) * 32 + q * 8;
            f32x4 xa = *(const f32x4*)xp;
            f32x4 xb = *(const f32x4*)(xp + 4);
            #pragma unroll
            for (int e = 0; e < 4; ++e) { ax[e] = (bf16)xa[e]; ax[4 + e] = (bf16)xb[e]; }
        }
        consume(fY, GSZ * eY);           // all blocks wrote h(t) buffer
        const bf16* hs = ((t & 1) ? gYb : gY) + m * 4096 + lane * 8;
        bf16x8 a[8];
        ld4g<FAST>(hs, a[0], a[1], a[2], a[3]);
        ld4g<FAST>(hs + 2048, a[4], a[5], a[6], a[7]);
        vmwait();
        f32x4 aR = Z, aZ = Z, aNH = Z, aNX = Z;
        #pragma unroll
        for (int kk = 0; kk < 8; ++kk) {
            aR  = MFMA(*(const bf16x8*)&sWgt[(0 * 9 + kk) * 512 + lane * 8], a[kk], aR);
            aZ  = MFMA(*(const bf16x8*)&sWgt[(1 * 9 + kk) * 512 + lane * 8], a[kk], aZ);
            aNH = MFMA(*(const bf16x8*)&sWgt[(2 * 9 + kk) * 512 + lane * 8], a[kk], aNH);
        }
        aR  = MFMA(*(const bf16x8*)&sWgt[(0 * 9 + 8) * 512 + lane * 8], ax, aR);
        aZ  = MFMA(*(const bf16x8*)&sWgt[(1 * 9 + 8) * 512 + lane * 8], ax, aZ);
        aNX = MFMA(*(const bf16x8*)&sWgt[(2 * 9 + 8) * 512 + lane * 8], ax, aNX);
        bf16* hd = (((t + 1) & 1) ? gYb : gY) + m * 4096;
        bf16x4 ov;
        #pragma unroll
        for (int r = 0; r < 4; ++r) {
            const float rg = sigm_f(aR[r] + bcr[r]);
            const float zg = sigm_f(aZ[r] + bcz[r]);
            const float nn = tanh_f(aNX[r] + bcn[r] + rg * (aNH[r] + bnr[r]));
            hreg[r] = nn + zg * (hreg[r] - nn);
            ov[r] = (bf16)hreg[r];
        }
        st4g<FAST>(hd + dY, ov);
        produce(fY, tid); ++eY;
    }
    // produce's barrier => all waves done with GRU weights in LDS

    // ---- stage ODE weight slices (overwrite GRU region) ----
    bf16* sW0 = sWgt;            // 8192 elems
    bf16* sW1 = sWgt + 8192;     // 16384 elems
    bf16* sW2 = sWgt + 24576;    // 8192 elems
    for (int i = tid; i < 1024; i += NTHR)
        *(bf16x8*)&sW0[i * 8] = *(const bf16x8*)&W0p[(size_t)j * 8192 + i * 8];
    for (int i = tid; i < 2048; i += NTHR)
        *(bf16x8*)&sW1[i * 8] = *(const bf16x8*)&W1p[(size_t)j * 16384 + i * 8];
    for (int i = tid; i < 1024; i += NTHR)
        *(bf16x8*)&sW2[i * 8] = *(const bf16x8*)&W2p[(size_t)j * 8192 + i * 8];
    __syncthreads();

    // ---- per-wave ODE constants; yreg = hreg (identical feat/batch ownership) ----
    f32x4 b0v[2], b1v[2];
    #pragma unroll
    for (int nt = 0; nt < 2; ++nt) {
        b0v[nt] = *(const f32x4*)&b0[32 * j + nt * 16 + q4];
        b1v[nt] = *(const f32x4*)&b1[32 * j + nt * 16 + q4];
    }
    const f32x4 b2v = *(const f32x4*)&b2[16 * j + q4];
    int dA[2];
    #pragma unroll
    for (int nt = 0; nt < 2; ++nt)
        dA[nt] = (j * 64 + (lm | (((4 * j + 2 * nt + (q >> 1)) & 3) << 4))) * 8 + (q & 1) * 4;

    f32x4 yreg = hreg;
    f32x4 kreg[5];

    // ---- Tsit5 loop (consume-before-stage) ----
    const int NSS = H * 10;
    for (int ss = 0; ss < NSS; ++ss) {
        consume(fY, GSZ * eY);
        if (ss && ss % 10 == 0)
            dec_unit<FAST>(gY, sWdec, sBdec, out, g, j, w, lane, H, ss / 10 - 1);
        ode_stage<0, FAST>(sW0, sW1, sW2, gY, gH1, gH2, fY, fH1, fH2, tid, w, lane,
                           b0v, b1v, b2v, dA, dY, yreg, kreg, eY, eH1, eH2);
        consume(fY, GSZ * eY);
        ode_stage<1, FAST>(sW0, sW1, sW2, gY, gH1, gH2, fY, fH1, fH2, tid, w, lane,
                           b0v, b1v, b2v, dA, dY, yreg, kreg, eY, eH1, eH2);
        consume(fY, GSZ * eY);
        ode_stage<2, FAST>(sW0, sW1, sW2, gY, gH1, gH2, fY, fH1, fH2, tid, w, lane,
                           b0v, b1v, b2v, dA, dY, yreg, kreg, eY, eH1, eH2);
        consume(fY, GSZ * eY);
        ode_stage<3, FAST>(sW0, sW1, sW2, gY, gH1, gH2, fY, fH1, fH2, tid, w, lane,
                           b0v, b1v, b2v, dA, dY, yreg, kreg, eY, eH1, eH2);
        consume(fY, GSZ * eY);
        ode_stage<4, FAST>(sW0, sW1, sW2, gY, gH1, gH2, fY, fH1, fH2, tid, w, lane,
                           b0v, b1v, b2v, dA, dY, yreg, kreg, eY, eH1, eH2);
        consume(fY, GSZ * eY);
        ode_stage<5, FAST>(sW0, sW1, sW2, gY, gH1, gH2, fY, fH1, fH2, tid, w, lane,
                           b0v, b1v, b2v, dA, dY, yreg, kreg, eY, eH1, eH2);
    }
    consume(fY, GSZ * eY);
    dec_unit<FAST>(gY, sWdec, sBdec, out, g, j, w, lane, H, H - 1);
}

__global__ void __launch_bounds__(NTHR, 4)
k_main(const float* __restrict__ x_seq, const int* __restrict__ cidx,
       const float* __restrict__ b_n, const float* __restrict__ b0,
       const float* __restrict__ b1, const float* __restrict__ b2,
       const float* __restrict__ W_dec, const float* __restrict__ b_dec,
       char* __restrict__ ws, float* __restrict__ out, int H) {
    __shared__ __align__(16) bf16 sWgt[32768];     // 64 KB
    __shared__ __align__(16) float sWdec[2048];    // 8 KB
    __shared__ float sBdec[8];
    __shared__ u32 mapL[NBLK];                     // 2 KB
    __shared__ int sMeta[3];

    const int tid = threadIdx.x, b = blockIdx.x;

    // ---- XCD map exchange (device-scope) ----
    u32* xmap = (u32*)(ws + WS_MAP);
    u32* gctr = (u32*)(ws + WS_MAP + 2048);
    u32 xcc;
    asm volatile("s_getreg_b32 %0, hwreg(HW_REG_XCC_ID)" : "=s"(xcc));
    if (tid == 0) {
        __hip_atomic_store(&xmap[b], xcc, __ATOMIC_RELEASE, __HIP_MEMORY_SCOPE_AGENT);
        __hip_atomic_fetch_add(gctr, 1u, __ATOMIC_ACQ_REL, __HIP_MEMORY_SCOPE_AGENT);
        while (__hip_atomic_load(gctr, __ATOMIC_ACQUIRE, __HIP_MEMORY_SCOPE_AGENT) < NBLK)
            __builtin_amdgcn_s_sleep(8);
    }
    __syncthreads();
    if (tid < NBLK)
        mapL[tid] = __hip_atomic_load(&xmap[tid], __ATOMIC_ACQUIRE, __HIP_MEMORY_SCOPE_AGENT);
    __syncthreads();

    // ---- dynamic groups: 16 blocks co-resident on one XCD; co-resident pairs
    //      interleave across the XCD's 4 groups (rank&3) for phase diversity ----
    if (tid == 0) {
        int cnt[8] = {0, 0, 0, 0, 0, 0, 0, 0};
        int rank = 0, bad = 0;
        const u32 my = mapL[b];
        for (int i = 0; i < NBLK; ++i) {
            const u32 x = mapL[i];
            if (x > 7u) bad = 1;
            else cnt[x]++;
            if (i < b && x == my) ++rank;
        }
        int ok = !bad;
        #pragma unroll
        for (int i = 0; i < 8; ++i) ok &= (cnt[i] == 64);
        sMeta[0] = ok;
        sMeta[1] = ok ? (int)(my * 4 + (rank & 3)) : (b >> 4);
        sMeta[2] = ok ? (rank >> 2) : (b & 15);
    }
    __syncthreads();
    const int ok = sMeta[0], g = sMeta[1], j = sMeta[2];
    __syncthreads();

    if (ok)
        body<true>(x_seq, cidx, b_n, b0, b1, b2, W_dec, b_dec, ws, out,
                   sWgt, sWdec, sBdec, H, g, j);
    else
        body<false>(x_seq, cidx, b_n, b0, b1, b2, W_dec, b_dec, ws, out,
                    sWgt, sWdec, sBdec, H, g, j);
}

// Pack fp32 weight [OUT][Ksrc] (cols koff..koff+K) into MFMA A-fragment order bf16:
// frag f = c*(K/32)+kk; lane's 8 elems = row c*16+(lane&15), k = kk*32+(lane>>4)*8+j
__global__ void k_pack(const float* __restrict__ src, bf16* __restrict__ dst,
                       int OUT, int K, int Ksrc, int koff) {
    const int total = (OUT * K) >> 3;
    for (int gg = blockIdx.x * blockDim.x + threadIdx.x; gg < total; gg += gridDim.x * blockDim.x) {
        const int lane = gg & 63, f = gg >> 6;
        const int KK = K >> 5;
        const int kk = f % KK, c = f / KK;
        const int col = c * 16 + (lane & 15);
        const int k0 = kk * 32 + ((lane >> 4) << 3);
        bf16x8 o;
        #pragma unroll
        for (int jj = 0; jj < 8; ++jj) o[jj] = (bf16)src[(size_t)col * Ksrc + koff + k0 + jj];
        *(bf16x8*)&dst[(size_t)gg * 8] = o;
    }
}

__global__ void k_bias(const float* __restrict__ W_ih, const float* __restrict__ b_ih,
                       float* __restrict__ bias_c) {
    const int i = blockIdx.x * blockDim.x + threadIdx.x;
    if (i < 64 * 768) {
        const int c = i / 768, n = i - c * 768;
        bias_c[i] = W_ih[(size_t)n * 96 + 32 + c] + b_ih[n];
    }
}

extern "C" void kernel_launch(void* const* d_in, const int* in_sizes, int n_in,
                              void* d_out, int out_size, void* d_ws, size_t ws_size,
                              hipStream_t stream) {
    const float* x_seq = (const float*)d_in[0];
    const int*   cidx  = (const int*)d_in[1];
    const float* W_ih  = (const float*)d_in[3];
    const float* W_hh  = (const float*)d_in[4];
    const float* b_ih  = (const float*)d_in[5];
    const float* b_n   = (const float*)d_in[6];
    const float* W0    = (const float*)d_in[7];
    const float* b0    = (const float*)d_in[8];
    const float* W1    = (const float*)d_in[9];
    const float* b1    = (const float*)d_in[10];
    const float* W2    = (const float*)d_in[11];
    const float* b2    = (const float*)d_in[12];
    const float* W_dec = (const float*)d_in[13];
    const float* b_dec = (const float*)d_in[14];
    float* out = (float*)d_out;
    const int H = out_size / (B_TOT * NT_OUT);
    char* ws = (char*)d_ws;

    // zero flags (32x256B) + xcd map (2KB) + gctr (every launch -> graph-replay safe)
    hipMemsetAsync(ws + WS_FLG, 0, 16384, stream);

    k_pack<<<64, 256, 0, stream>>>(W0, (bf16*)(ws + WS_W0), 512, 256, 256, 0);
    k_pack<<<128, 256, 0, stream>>>(W1, (bf16*)(ws + WS_W1), 512, 512, 512, 0);
    k_pack<<<64, 256, 0, stream>>>(W2, (bf16*)(ws + WS_W2), 256, 512, 512, 0);
    k_pack<<<96, 256, 0, stream>>>(W_hh, (bf16*)(ws + WS_WHH), 768, 256, 256, 0);
    k_pack<<<12, 256, 0, stream>>>(W_ih, (bf16*)(ws + WS_WIH), 768, 32, 96, 0);
    k_bias<<<(64 * 768 + 255) / 256, 256, 0, stream>>>(W_ih, b_ih, (float*)(ws + WS_BC));

    k_main<<<NBLK, NTHR, 0, stream>>>(x_seq, cidx, b_n, b0, b1, b2, W_dec, b_dec,
                                      ws, out, H);
}

// Round 12
// 5655.762 us; speedup vs baseline: 3.5497x; 3.5497x over previous
//
#include <hip/hip_runtime.h>

typedef __bf16 bf16;
typedef __bf16 bf16x8 __attribute__((ext_vector_type(8)));
typedef __bf16 bf16x4 __attribute__((ext_vector_type(4)));
typedef float  f32x4  __attribute__((ext_vector_type(4)));
typedef unsigned int u32;

#define B_TOT 4096
#define T_SEQ 64
#define NT_OUT 8
#define NTHR 512
#define NBLK 256
#define GSZ  8

// ---- ws layout (bytes) ----
#define WS_W0   0           // 512x256 bf16 packed frags
#define WS_W1   262144
#define WS_W2   786432
#define WS_WHH  1048576
#define WS_WIH  1441792
#define WS_BC   1490944     // 64x768 f32
#define WS_GY   1703936     // 32 groups x 64KB   (y_stage / GRU h buf0)
#define WS_GYB  3801088     // 32 x 64KB          (GRU h buf1)
#define WS_GH1  5898240     // 32 x 128KB
#define WS_GH2  10092544    // 32 x 128KB
#define WS_FLG  14286848    // 32 groups x 512B: fY@+0, fH1@+64B, fH2@+128B (no aliasing)
#define WS_MAP  14303232    // 256 u32 xcd map; gctr @ +1024

// Tsit5 tableau
constexpr float A21 = 0.161f;
constexpr float A31 = -0.008480655492356989f, A32 = 0.335480655492357f;
constexpr float A41 = 2.8971530571054935f, A42 = -6.359448489975075f, A43 = 4.362295432869581f;
constexpr float A51 = 5.325864828439257f, A52 = -11.748883564062828f, A53 = 7.4955393428898365f, A54 = -0.09249506636175525f;
constexpr float A61 = 5.86145544294642f, A62 = -12.92096931784711f, A63 = 8.159367898576159f, A64 = -0.071584973281401f, A65 = -0.028269050394068383f;
constexpr float BC1 = 0.09646076681806523f, BC2 = 0.01f, BC3 = 0.4798896504144996f;
constexpr float BC4 = 1.379008574103742f, BC5 = -3.290069515436081f, BC6 = 2.324710524099774f;
constexpr float DT = 0.1f;
constexpr float BROW[5][5] = {
    {A21, 0, 0, 0, 0},
    {A31, A32, 0, 0, 0},
    {A41, A42, A43, 0, 0},
    {A51, A52, A53, A54, 0},
    {A61, A62, A63, A64, A65}};
constexpr float FCF[6] = {BC1, BC2, BC3, BC4, BC5, BC6};

__device__ __forceinline__ f32x4 MFMA(bf16x8 a, bf16x8 b, f32x4 c) {
    return __builtin_amdgcn_mfma_f32_16x16x32_bf16(a, b, c, 0, 0, 0);
}
__device__ __forceinline__ float eluf(float x) { return x > 0.f ? x : __expf(x) - 1.f; }
__device__ __forceinline__ float sigm_f(float x) { return 1.f / (1.f + __expf(-x)); }
__device__ __forceinline__ float tanh_f(float x) { return 1.f - 2.f / (__expf(2.f * x) + 1.f); }

// ---- coherent global access (FAST: group formed on one XCD -> sc0 only) ----
template<bool FAST>
__device__ __forceinline__ void ld4g(const bf16* p, bf16x8& a0, bf16x8& a1, bf16x8& a2, bf16x8& a3) {
    if constexpr (FAST) {
        asm volatile(
            "global_load_dwordx4 %0, %4, off sc0\n\t"
            "global_load_dwordx4 %1, %4, off offset:1024 sc0\n\t"
            "global_load_dwordx4 %2, %4, off offset:2048 sc0\n\t"
            "global_load_dwordx4 %3, %4, off offset:3072 sc0"
            : "=&v"(a0), "=&v"(a1), "=&v"(a2), "=&v"(a3) : "v"(p) : "memory");
    } else {
        asm volatile(
            "global_load_dwordx4 %0, %4, off sc0 sc1\n\t"
            "global_load_dwordx4 %1, %4, off offset:1024 sc0 sc1\n\t"
            "global_load_dwordx4 %2, %4, off offset:2048 sc0 sc1\n\t"
            "global_load_dwordx4 %3, %4, off offset:3072 sc0 sc1"
            : "=&v"(a0), "=&v"(a1), "=&v"(a2), "=&v"(a3) : "v"(p) : "memory");
    }
}
template<bool FAST>
__device__ __forceinline__ bf16x8 ld1g(const bf16* p) {
    bf16x8 a;
    if constexpr (FAST)
        asm volatile("global_load_dwordx4 %0, %1, off sc0\n\ts_waitcnt vmcnt(0)"
                     : "=v"(a) : "v"(p) : "memory");
    else
        asm volatile("global_load_dwordx4 %0, %1, off sc0 sc1\n\ts_waitcnt vmcnt(0)"
                     : "=v"(a) : "v"(p) : "memory");
    return a;
}
template<bool FAST>
__device__ __forceinline__ void st4g(bf16* p, bf16x4 v) {
    if constexpr (FAST) *(bf16x4*)p = v;
    else asm volatile("global_store_dwordx2 %0, %1, off sc0 sc1" :: "v"(p), "v"(v) : "memory");
}
// counted vmem wait: oldest (outstanding-N) loads are complete after this
template<int N>
__device__ __forceinline__ void vmwaitN() {
    asm volatile("s_waitcnt vmcnt(%0)" :: "n"(N) : "memory");
    __builtin_amdgcn_sched_barrier(0);
}

// ---- block-lockstep group rendezvous (round-5/9 proven semantics) ----
__device__ __forceinline__ void produce(u32* f, int tid) {
    asm volatile("s_waitcnt vmcnt(0)" ::: "memory");   // own wave's stores acked
    __syncthreads();                                   // all waves drained
    if (tid == 0) __hip_atomic_fetch_add(f, 1u, __ATOMIC_RELAXED, __HIP_MEMORY_SCOPE_AGENT);
}
__device__ __forceinline__ void consume(const u32* f, u32 tgt, int tid) {
    if (tid == 0) {
        while (__hip_atomic_load(f, __ATOMIC_RELAXED, __HIP_MEMORY_SCOPE_AGENT) < tgt)
            __builtin_amdgcn_s_sleep(1);
    }
    __syncthreads();
}

// ---- one Tsit5 stage; wave = batch tile m = w (no redundant act reads) ----
template<int ST, bool FAST>
__device__ __forceinline__ void ode_stage(
    const bf16* sW0, const bf16* sW1, const bf16* sW2,
    bf16* gY, bf16* gH1, bf16* gH2,
    u32* fY, u32* fH1, u32* fH2, int tid, int w, int lane,
    const f32x4 (&b0v)[4], const f32x4 (&b1v)[4], const f32x4 (&b2v)[2],
    const int (&dA)[4], const int (&dY)[2],
    f32x4 (&yreg)[2], f32x4 (&kreg)[5][2],
    u32& eY, u32& eH1, u32& eH2) {
    const f32x4 Z = {0.f, 0.f, 0.f, 0.f};
    // ---- L0: h1-slice = elu(W0s x y^T + b0s), A=weight(LDS), B=act(L2) ----
    {
        bf16x8 a[8];
        const bf16* p = gY + w * 4096 + lane * 8;
        ld4g<FAST>(p, a[0], a[1], a[2], a[3]);
        ld4g<FAST>(p + 2048, a[4], a[5], a[6], a[7]);
        f32x4 acc[4] = {Z, Z, Z, Z};
        vmwaitN<4>();                        // a[0..3] ready; a[4..7] in flight
        #pragma unroll
        for (int kk = 0; kk < 4; ++kk)
            #pragma unroll
            for (int nt = 0; nt < 4; ++nt)
                acc[nt] = MFMA(*(const bf16x8*)&sW0[(nt * 8 + kk) * 512 + lane * 8], a[kk], acc[nt]);
        vmwaitN<0>();
        #pragma unroll
        for (int kk = 4; kk < 8; ++kk)
            #pragma unroll
            for (int nt = 0; nt < 4; ++nt)
                acc[nt] = MFMA(*(const bf16x8*)&sW0[(nt * 8 + kk) * 512 + lane * 8], a[kk], acc[nt]);
        #pragma unroll
        for (int nt = 0; nt < 4; ++nt) {
            bf16x4 ov;
            #pragma unroll
            for (int r = 0; r < 4; ++r) ov[r] = (bf16)eluf(acc[nt][r] + b0v[nt][r]);
            st4g<FAST>(gH1 + w * 8192 + dA[nt], ov);
        }
    }
    produce(fH1, tid); ++eH1;
    consume(fH1, GSZ * eH1, tid);
    // ---- L1: h2-slice = elu(W1s x h1^T + b1s) ----
    {
        bf16x8 a[16];
        const bf16* p = gH1 + w * 8192 + lane * 8;
        ld4g<FAST>(p, a[0], a[1], a[2], a[3]);
        ld4g<FAST>(p + 2048, a[4], a[5], a[6], a[7]);
        ld4g<FAST>(p + 4096, a[8], a[9], a[10], a[11]);
        ld4g<FAST>(p + 6144, a[12], a[13], a[14], a[15]);
        f32x4 acc[4] = {Z, Z, Z, Z};
        vmwaitN<8>();                        // a[0..7] ready
        #pragma unroll
        for (int kk = 0; kk < 8; ++kk)
            #pragma unroll
            for (int nt = 0; nt < 4; ++nt)
                acc[nt] = MFMA(*(const bf16x8*)&sW1[(nt * 16 + kk) * 512 + lane * 8], a[kk], acc[nt]);
        vmwaitN<0>();
        #pragma unroll
        for (int kk = 8; kk < 16; ++kk)
            #pragma unroll
            for (int nt = 0; nt < 4; ++nt)
                acc[nt] = MFMA(*(const bf16x8*)&sW1[(nt * 16 + kk) * 512 + lane * 8], a[kk], acc[nt]);
        #pragma unroll
        for (int nt = 0; nt < 4; ++nt) {
            bf16x4 ov;
            #pragma unroll
            for (int r = 0; r < 4; ++r) ov[r] = (bf16)eluf(acc[nt][r] + b1v[nt][r]);
            st4g<FAST>(gH2 + w * 8192 + dA[nt], ov);
        }
    }
    produce(fH2, tid); ++eH2;
    consume(fH2, GSZ * eH2, tid);
    // ---- L2: k-slice = W2s x h2^T + b2s; Tsit5 build in registers ----
    {
        bf16x8 a[16];
        const bf16* p = gH2 + w * 8192 + lane * 8;
        ld4g<FAST>(p, a[0], a[1], a[2], a[3]);
        ld4g<FAST>(p + 2048, a[4], a[5], a[6], a[7]);
        ld4g<FAST>(p + 4096, a[8], a[9], a[10], a[11]);
        ld4g<FAST>(p + 6144, a[12], a[13], a[14], a[15]);
        f32x4 acc[2] = {Z, Z};
        vmwaitN<8>();
        #pragma unroll
        for (int kk = 0; kk < 8; ++kk)
            #pragma unroll
            for (int nt = 0; nt < 2; ++nt)
                acc[nt] = MFMA(*(const bf16x8*)&sW2[(nt * 16 + kk) * 512 + lane * 8], a[kk], acc[nt]);
        vmwaitN<0>();
        #pragma unroll
        for (int kk = 8; kk < 16; ++kk)
            #pragma unroll
            for (int nt = 0; nt < 2; ++nt)
                acc[nt] = MFMA(*(const bf16x8*)&sW2[(nt * 16 + kk) * 512 + lane * 8], a[kk], acc[nt]);
        #pragma unroll
        for (int nt = 0; nt < 2; ++nt) {
            f32x4 kv;
            #pragma unroll
            for (int r = 0; r < 4; ++r) kv[r] = acc[nt][r] + b2v[nt][r];
            f32x4 yst;
            if constexpr (ST < 5) {
                kreg[ST][nt] = kv;
                yst = yreg[nt];
                #pragma unroll
                for (int s = 0; s <= ST; ++s) {
                    const float c = DT * BROW[ST][s];
                    #pragma unroll
                    for (int r = 0; r < 4; ++r) yst[r] += c * kreg[s][nt][r];
                }
            } else {
                #pragma unroll
                for (int s = 0; s < 5; ++s) {
                    const float c = DT * FCF[s];
                    #pragma unroll
                    for (int r = 0; r < 4; ++r) yreg[nt][r] += c * kreg[s][nt][r];
                }
                #pragma unroll
                for (int r = 0; r < 4; ++r) yreg[nt][r] += (DT * FCF[5]) * kv[r];
                yst = yreg[nt];
            }
            bf16x4 ov;
            #pragma unroll
            for (int r = 0; r < 4; ++r) ov[r] = (bf16)yst[r];
            st4g<FAST>(gY + w * 4096 + dY[nt], ov);
        }
    }
    produce(fY, tid); ++eY;
}

// ---- decode: block rank j emits its group's batch tile j for unit u ----
template<bool FAST>
__device__ __forceinline__ void dec_unit(const bf16* gY, const float* sWdec, const float* sBdec,
                                         float* out, int g, int j, int w, int lane, int H, int u) {
    const int rloc = 2 * w + (lane >> 5);
    const int li = lane & 31;
    const bf16* p = gY + (size_t)j * 4096 + (((li >> 2) * 64 + (li & 3) * 16 + rloc)) * 8;
    bf16x8 yv = ld1g<FAST>(p);
    const int f0 = li * 8;
    float acc[8];
    #pragma unroll
    for (int t = 0; t < 8; ++t) acc[t] = 0.f;
    #pragma unroll
    for (int e = 0; e < 8; ++e) {
        const float yf = (float)yv[e];
        #pragma unroll
        for (int t = 0; t < 8; ++t) acc[t] += yf * sWdec[t * 256 + f0 + e];
    }
    #pragma unroll
    for (int k = 1; k < 32; k <<= 1)
        #pragma unroll
        for (int t = 0; t < 8; ++t) acc[t] += __shfl_xor(acc[t], k, 64);
    if (li == 0) {
        const size_t row = (size_t)g * 128 + 16 * j + rloc;
        #pragma unroll
        for (int t = 0; t < 8; ++t) out[(row * H + u) * NT_OUT + t] = acc[t] + sBdec[t];
    }
}

template<bool FAST>
__device__ void body(const float* __restrict__ x_seq, const int* __restrict__ cidx,
                     const float* __restrict__ b_n, const float* __restrict__ b0,
                     const float* __restrict__ b1, const float* __restrict__ b2,
                     const float* __restrict__ W_dec, const float* __restrict__ b_dec,
                     char* __restrict__ ws, float* __restrict__ out,
                     bf16* sWgt, float* sWdec, float* sBdec,
                     int H, int g, int j) {
    const int tid = threadIdx.x, w = tid >> 6, lane = tid & 63;
    const int lm = lane & 15, q = lane >> 4, q4 = q << 2;
    const int grow0 = g * 128;

    const bf16* W0p  = (const bf16*)(ws + WS_W0);
    const bf16* W1p  = (const bf16*)(ws + WS_W1);
    const bf16* W2p  = (const bf16*)(ws + WS_W2);
    const bf16* WhhP = (const bf16*)(ws + WS_WHH);
    const bf16* WihP = (const bf16*)(ws + WS_WIH);
    const float* bias_c = (const float*)(ws + WS_BC);
    bf16* gY  = (bf16*)(ws + WS_GY)  + (size_t)g * 32768;
    bf16* gYb = (bf16*)(ws + WS_GYB) + (size_t)g * 32768;
    bf16* gH1 = (bf16*)(ws + WS_GH1) + (size_t)g * 65536;
    bf16* gH2 = (bf16*)(ws + WS_GH2) + (size_t)g * 65536;
    // 512B per group: fY@+0, fH1@+64B, fH2@+128B — all strictly inside the stride
    u32* fl  = (u32*)(ws + WS_FLG + (size_t)g * 512);
    u32 *fY = fl, *fH1 = fl + 16, *fH2 = fl + 32;

    u32 eY = 0, eH1 = 0, eH2 = 0;

    // ---- stage decode weights + GRU weight slices into LDS ----
    for (int i = tid; i < 2048; i += NTHR) sWdec[i] = W_dec[i];
    if (tid < 8) sBdec[tid] = b_dec[tid];
    for (int i = tid; i < 54 * 64; i += NTHR) {
        const int fr = i >> 6, l = i & 63;
        const int tau = fr / 9, kk = fr % 9;
        const int gam = tau >> 1, p = tau & 1;
        const int c = gam * 16 + 2 * j + p;
        const bf16* src = (kk < 8) ? &WhhP[(((size_t)c) * 8 + kk) * 512 + l * 8]
                                   : &WihP[((size_t)c) * 512 + l * 8];
        *(bf16x8*)&sWgt[((size_t)fr) * 512 + l * 8] = *(const bf16x8*)src;
    }

    // ---- GRU per-wave constants (wave = batch tile m = w) ----
    const int m = w;
    float bcr[2][4], bcz[2][4], bcn[2][4], bnr[2][4];
    {
        const int c = cidx[grow0 + 16 * m + lm];
        #pragma unroll
        for (int p = 0; p < 2; ++p)
            #pragma unroll
            for (int r = 0; r < 4; ++r) {
                const int F = 32 * j + p * 16 + q4 + r;
                bcr[p][r] = bias_c[(size_t)c * 768 + F];
                bcz[p][r] = bias_c[(size_t)c * 768 + 256 + F];
                bcn[p][r] = bias_c[(size_t)c * 768 + 512 + F];
                bnr[p][r] = b_n[F];
            }
    }
    int dY[2];
    #pragma unroll
    for (int p = 0; p < 2; ++p)
        dY[p] = (j * 64 + ((4 * j + 2 * p + (q >> 1)) & 3) * 16 + lm) * 8 + (q & 1) * 4;

    // h0 = 0 (wave w zeroes its feat slice of its tile)
    {
        bf16x4 z4;
        #pragma unroll
        for (int r = 0; r < 4; ++r) z4[r] = (bf16)0.f;
        st4g<FAST>(gY + m * 4096 + dY[0], z4);
        st4g<FAST>(gY + m * 4096 + dY[1], z4);
    }
    produce(fY, tid); ++eY;     // also covers LDS weight staging (syncthreads inside)

    // ---- GRU scan (block-lockstep) ----
    f32x4 hreg[2] = {{0.f, 0.f, 0.f, 0.f}, {0.f, 0.f, 0.f, 0.f}};
    const f32x4 Z = {0.f, 0.f, 0.f, 0.f};
    for (int t = 0; t < T_SEQ; ++t) {
        bf16x8 ax;
        {
            const float* xp = x_seq + (((size_t)(grow0 + 16 * m + lm)) * T_SEQ + t) * 32 + q * 8;
            f32x4 xa = *(const f32x4*)xp;
            f32x4 xb = *(const f32x4*)(xp + 4);
            #pragma unroll
            for (int e = 0; e < 4; ++e) { ax[e] = (bf16)xa[e]; ax[4 + e] = (bf16)xb[e]; }
        }
        consume(fY, GSZ * eY, tid);      // all blocks wrote h(t) buffer
        const bf16* hs = ((t & 1) ? gYb : gY) + m * 4096 + lane * 8;
        bf16x8 a[8];
        ld4g<FAST>(hs, a[0], a[1], a[2], a[3]);
        ld4g<FAST>(hs + 2048, a[4], a[5], a[6], a[7]);
        f32x4 rz[4] = {Z, Z, Z, Z}, nH[2] = {Z, Z}, nX[2] = {Z, Z};
        vmwaitN<4>();
        #pragma unroll
        for (int kk = 0; kk < 4; ++kk) {
            #pragma unroll
            for (int p = 0; p < 2; ++p) {
                rz[p]     = MFMA(*(const bf16x8*)&sWgt[((0 + p) * 9 + kk) * 512 + lane * 8], a[kk], rz[p]);
                rz[2 + p] = MFMA(*(const bf16x8*)&sWgt[((2 + p) * 9 + kk) * 512 + lane * 8], a[kk], rz[2 + p]);
                nH[p]     = MFMA(*(const bf16x8*)&sWgt[((4 + p) * 9 + kk) * 512 + lane * 8], a[kk], nH[p]);
            }
        }
        vmwaitN<0>();
        #pragma unroll
        for (int kk = 4; kk < 8; ++kk) {
            #pragma unroll
            for (int p = 0; p < 2; ++p) {
                rz[p]     = MFMA(*(const bf16x8*)&sWgt[((0 + p) * 9 + kk) * 512 + lane * 8], a[kk], rz[p]);
                rz[2 + p] = MFMA(*(const bf16x8*)&sWgt[((2 + p) * 9 + kk) * 512 + lane * 8], a[kk], rz[2 + p]);
                nH[p]     = MFMA(*(const bf16x8*)&sWgt[((4 + p) * 9 + kk) * 512 + lane * 8], a[kk], nH[p]);
            }
        }
        #pragma unroll
        for (int p = 0; p < 2; ++p) {
            rz[p]     = MFMA(*(const bf16x8*)&sWgt[((0 + p) * 9 + 8) * 512 + lane * 8], ax, rz[p]);
            rz[2 + p] = MFMA(*(const bf16x8*)&sWgt[((2 + p) * 9 + 8) * 512 + lane * 8], ax, rz[2 + p]);
            nX[p]     = MFMA(*(const bf16x8*)&sWgt[((4 + p) * 9 + 8) * 512 + lane * 8], ax, nX[p]);
        }
        bf16* hd = (((t + 1) & 1) ? gYb : gY) + m * 4096;
        #pragma unroll
        for (int p = 0; p < 2; ++p) {
            bf16x4 ov;
            #pragma unroll
            for (int r = 0; r < 4; ++r) {
                const float rg = sigm_f(rz[p][r] + bcr[p][r]);
                const float zg = sigm_f(rz[2 + p][r] + bcz[p][r]);
                const float nn = tanh_f(nX[p][r] + bcn[p][r] + rg * (nH[p][r] + bnr[p][r]));
                hreg[p][r] = nn + zg * (hreg[p][r] - nn);
                ov[r] = (bf16)hreg[p][r];
            }
            st4g<FAST>(hd + dY[p], ov);
        }
        produce(fY, tid); ++eY;
    }
    // last produce's __syncthreads => all waves done with GRU weights in LDS

    // ---- stage ODE weight slices (overwrite GRU region) ----
    bf16* sW0 = sWgt;            // 16384 elems
    bf16* sW1 = sWgt + 16384;    // 32768 elems
    bf16* sW2 = sWgt + 49152;    // 16384 elems
    for (int i = tid; i < 2048; i += NTHR)
        *(bf16x8*)&sW0[i * 8] = *(const bf16x8*)&W0p[(size_t)j * 16384 + i * 8];
    for (int i = tid; i < 4096; i += NTHR)
        *(bf16x8*)&sW1[i * 8] = *(const bf16x8*)&W1p[(size_t)j * 32768 + i * 8];
    for (int i = tid; i < 2048; i += NTHR)
        *(bf16x8*)&sW2[i * 8] = *(const bf16x8*)&W2p[(size_t)j * 16384 + i * 8];
    __syncthreads();

    // ---- per-wave ODE constants; yreg = hreg (identical feat/batch ownership) ----
    f32x4 b0v[4], b1v[4], b2v[2];
    #pragma unroll
    for (int nt = 0; nt < 4; ++nt) {
        b0v[nt] = *(const f32x4*)&b0[64 * j + nt * 16 + q4];
        b1v[nt] = *(const f32x4*)&b1[64 * j + nt * 16 + q4];
    }
    #pragma unroll
    for (int nt = 0; nt < 2; ++nt) b2v[nt] = *(const f32x4*)&b2[32 * j + nt * 16 + q4];
    int dA[4];
    #pragma unroll
    for (int nt = 0; nt < 4; ++nt)
        dA[nt] = ((2 * j + (nt >> 1)) * 64 + ((8 * j + 2 * nt + (q >> 1)) & 3) * 16 + lm) * 8 + (q & 1) * 4;

    f32x4 yreg[2] = {hreg[0], hreg[1]};
    f32x4 kreg[5][2];

    // ---- Tsit5 loop (consume-before-stage) ----
    const int NSS = H * 10;
    for (int ss = 0; ss < NSS; ++ss) {
        consume(fY, GSZ * eY, tid);
        if (ss && ss % 10 == 0)
            dec_unit<FAST>(gY, sWdec, sBdec, out, g, j, w, lane, H, ss / 10 - 1);
        ode_stage<0, FAST>(sW0, sW1, sW2, gY, gH1, gH2, fY, fH1, fH2, tid, w, lane,
                           b0v, b1v, b2v, dA, dY, yreg, kreg, eY, eH1, eH2);
        consume(fY, GSZ * eY, tid);
        ode_stage<1, FAST>(sW0, sW1, sW2, gY, gH1, gH2, fY, fH1, fH2, tid, w, lane,
                           b0v, b1v, b2v, dA, dY, yreg, kreg, eY, eH1, eH2);
        consume(fY, GSZ * eY, tid);
        ode_stage<2, FAST>(sW0, sW1, sW2, gY, gH1, gH2, fY, fH1, fH2, tid, w, lane,
                           b0v, b1v, b2v, dA, dY, yreg, kreg, eY, eH1, eH2);
        consume(fY, GSZ * eY, tid);
        ode_stage<3, FAST>(sW0, sW1, sW2, gY, gH1, gH2, fY, fH1, fH2, tid, w, lane,
                           b0v, b1v, b2v, dA, dY, yreg, kreg, eY, eH1, eH2);
        consume(fY, GSZ * eY, tid);
        ode_stage<4, FAST>(sW0, sW1, sW2, gY, gH1, gH2, fY, fH1, fH2, tid, w, lane,
                           b0v, b1v, b2v, dA, dY, yreg, kreg, eY, eH1, eH2);
        consume(fY, GSZ * eY, tid);
        ode_stage<5, FAST>(sW0, sW1, sW2, gY, gH1, gH2, fY, fH1, fH2, tid, w, lane,
                           b0v, b1v, b2v, dA, dY, yreg, kreg, eY, eH1, eH2);
    }
    consume(fY, GSZ * eY, tid);
    dec_unit<FAST>(gY, sWdec, sBdec, out, g, j, w, lane, H, H - 1);
}

__global__ void __launch_bounds__(NTHR, 2)
k_main(const float* __restrict__ x_seq, const int* __restrict__ cidx,
       const float* __restrict__ b_n, const float* __restrict__ b0,
       const float* __restrict__ b1, const float* __restrict__ b2,
       const float* __restrict__ W_dec, const float* __restrict__ b_dec,
       char* __restrict__ ws, float* __restrict__ out, int H) {
    __shared__ __align__(16) bf16 sWgt[65536];     // 128 KB
    __shared__ __align__(16) float sWdec[2048];    // 8 KB
    __shared__ float sBdec[8];
    __shared__ u32 mapL[NBLK];
    __shared__ int sMeta[3];

    const int tid = threadIdx.x, b = blockIdx.x;

    // ---- XCD map exchange (device-scope) ----
    u32* xmap = (u32*)(ws + WS_MAP);
    u32* gctr = (u32*)(ws + WS_MAP + 1024);
    u32 xcc;
    asm volatile("s_getreg_b32 %0, hwreg(HW_REG_XCC_ID)" : "=s"(xcc));
    if (tid == 0) {
        __hip_atomic_store(&xmap[b], xcc, __ATOMIC_RELEASE, __HIP_MEMORY_SCOPE_AGENT);
        __hip_atomic_fetch_add(gctr, 1u, __ATOMIC_ACQ_REL, __HIP_MEMORY_SCOPE_AGENT);
        while (__hip_atomic_load(gctr, __ATOMIC_ACQUIRE, __HIP_MEMORY_SCOPE_AGENT) < NBLK)
            __builtin_amdgcn_s_sleep(8);
    }
    __syncthreads();
    if (tid < NBLK)
        mapL[tid] = __hip_atomic_load(&xmap[tid], __ATOMIC_ACQUIRE, __HIP_MEMORY_SCOPE_AGENT);
    __syncthreads();

    // ---- dynamic group formation: groups = 8 blocks co-resident on one XCD ----
    if (tid == 0) {
        int cnt[8] = {0, 0, 0, 0, 0, 0, 0, 0};
        int rank = 0, bad = 0;
        const u32 my = mapL[b];
        for (int i = 0; i < NBLK; ++i) {
            const u32 x = mapL[i];
            if (x > 7u) bad = 1;
            else cnt[x]++;
            if (i < b && x == my) ++rank;
        }
        int ok = !bad;
        #pragma unroll
        for (int i = 0; i < 8; ++i) ok &= (cnt[i] == 32);
        sMeta[0] = ok;
        sMeta[1] = ok ? (int)(my * 4 + (rank >> 3)) : ((b & 7) * 4 + (b >> 6));
        sMeta[2] = ok ? (rank & 7) : ((b >> 3) & 7);
    }
    __syncthreads();
    const int ok = sMeta[0], g = sMeta[1], j = sMeta[2];
    __syncthreads();

    if (ok)
        body<true>(x_seq, cidx, b_n, b0, b1, b2, W_dec, b_dec, ws, out,
                   sWgt, sWdec, sBdec, H, g, j);
    else
        body<false>(x_seq, cidx, b_n, b0, b1, b2, W_dec, b_dec, ws, out,
                    sWgt, sWdec, sBdec, H, g, j);
}

// Pack fp32 weight [OUT][Ksrc] (cols koff..koff+K) into MFMA A-fragment order bf16:
// frag f = c*(K/32)+kk; lane's 8 elems = row c*16+(lane&15), k = kk*32+(lane>>4)*8+j
__global__ void k_pack(const float* __restrict__ src, bf16* __restrict__ dst,
                       int OUT, int K, int Ksrc, int koff) {
    const int total = (OUT * K) >> 3;
    for (int gg = blockIdx.x * blockDim.x + threadIdx.x; gg < total; gg += gridDim.x * blockDim.x) {
        const int lane = gg & 63, f = gg >> 6;
        const int KK = K >> 5;
        const int kk = f % KK, c = f / KK;
        const int col = c * 16 + (lane & 15);
        const int k0 = kk * 32 + ((lane >> 4) << 3);
        bf16x8 o;
        #pragma unroll
        for (int jj = 0; jj < 8; ++jj) o[jj] = (bf16)src[(size_t)col * Ksrc + koff + k0 + jj];
        *(bf16x8*)&dst[(size_t)gg * 8] = o;
    }
}

__global__ void k_bias(const float* __restrict__ W_ih, const float* __restrict__ b_ih,
                       float* __restrict__ bias_c) {
    const int i = blockIdx.x * blockDim.x + threadIdx.x;
    if (i < 64 * 768) {
        const int c = i / 768, n = i - c * 768;
        bias_c[i] = W_ih[(size_t)n * 96 + 32 + c] + b_ih[n];
    }
}

extern "C" void kernel_launch(void* const* d_in, const int* in_sizes, int n_in,
                              void* d_out, int out_size, void* d_ws, size_t ws_size,
                              hipStream_t stream) {
    const float* x_seq = (const float*)d_in[0];
    const int*   cidx  = (const int*)d_in[1];
    const float* W_ih  = (const float*)d_in[3];
    const float* W_hh  = (const float*)d_in[4];
    const float* b_ih  = (const float*)d_in[5];
    const float* b_n   = (const float*)d_in[6];
    const float* W0    = (const float*)d_in[7];
    const float* b0    = (const float*)d_in[8];
    const float* W1    = (const float*)d_in[9];
    const float* b1    = (const float*)d_in[10];
    const float* W2    = (const float*)d_in[11];
    const float* b2    = (const float*)d_in[12];
    const float* W_dec = (const float*)d_in[13];
    const float* b_dec = (const float*)d_in[14];
    float* out = (float*)d_out;
    const int H = out_size / (B_TOT * NT_OUT);
    char* ws = (char*)d_ws;

    // zero flags (32x512B) + xcd map + gctr (every launch -> graph-replay safe)
    hipMemsetAsync(ws + WS_FLG, 0, 20480, stream);

    k_pack<<<64, 256, 0, stream>>>(W0, (bf16*)(ws + WS_W0), 512, 256, 256, 0);
    k_pack<<<128, 256, 0, stream>>>(W1, (bf16*)(ws + WS_W1), 512, 512, 512, 0);
    k_pack<<<64, 256, 0, stream>>>(W2, (bf16*)(ws + WS_W2), 256, 512, 512, 0);
    k_pack<<<96, 256, 0, stream>>>(W_hh, (bf16*)(ws + WS_WHH), 768, 256, 256, 0);
    k_pack<<<12, 256, 0, stream>>>(W_ih, (bf16*)(ws + WS_WIH), 768, 32, 96, 0);
    k_bias<<<(64 * 768 + 255) / 256, 256, 0, stream>>>(W_ih, b_ih, (float*)(ws + WS_BC));

    k_main<<<NBLK, NTHR, 0, stream>>>(x_seq, cidx, b_n, b0, b1, b2, W_dec, b_dec,
                                      ws, out, H);
}